// Round 8
// baseline (14.170 us; speedup 1.0000x reference)
//
#include <hip/hip_runtime.h>

#define TIMESTEPS 1000
#define BATCH 64
#define HH 256
#define WW 256
#define ROWS_PER_WAVE 4
#define WAVES_PER_BLOCK 4
#define NROWS (BATCH * HH)                                   // 16384
#define NBLOCKS (NROWS / (ROWS_PER_WAVE * WAVES_PER_BLOCK))  // 1024
#define HBINS 1024                                           // bins padded 1000 -> 1024

typedef short s16x2 __attribute__((ext_vector_type(2)));

// Round-7 structure (12.76us) with the scatter atomics replaced by plain
// ds_write under a monotone y-mapping:
//   y = j*64 + lane  (j ascending)
// - across store instructions: later j => strictly larger y than ALL earlier
//   j's (j*64 > j'*64+63), so last-write-wins == max-y
// - within one store instruction: LDS collision rule = highest lane wins,
//   and y is monotone in lane => winner is max-y
// => exact scatter-max semantics at ~half the LDS bank work (no RMW).
// Loads become stride-64 dword loads (64 contiguous lanes each, coalesced).
__global__ __launch_bounds__(256) void holo_mse_kernel(
    const float* __restrict__ rec, const float* __restrict__ tgt,
    unsigned int* __restrict__ partials)
{
    __shared__ __align__(16) unsigned int hist[WAVES_PER_BLOCK][2][HBINS]; // 32 KB

    const int tid  = threadIdx.x;
    const int wave = tid >> 6;
    const int lane = tid & 63;

    unsigned int* hr = &hist[wave][0][0];
    unsigned int* ht = &hist[wave][1][0];

    // one-time init (gen 0 == invalid); contiguous b128 writes, uniform banks
    const uint4 z4 = make_uint4(0u, 0u, 0u, 0u);
    #pragma unroll
    for (int k = 0; k < 4; ++k) {
        *(uint4*)&hr[k * 256 + lane * 4] = z4;
        *(uint4*)&ht[k * 256 + lane * 4] = z4;
    }
    __builtin_amdgcn_wave_barrier();

    const int row0 = blockIdx.x * (ROWS_PER_WAVE * WAVES_PER_BLOCK) + wave * ROWS_PER_WAVE;

    unsigned int acc = 0;

    #pragma unroll
    for (int r = 0; r < ROWS_PER_WAVE; ++r) {
        const int row = row0 + r;
        const unsigned int genHi = (unsigned int)(r + 1) << 8;   // 1..4
        const float* rrow = rec + (size_t)row * WW;
        const float* trow = tgt + (size_t)row * WW;

        // scatter: ascending-j plain stores; aliasing (same t, different j)
        // forces the compiler to keep program order, HW DS is in-order.
        #pragma unroll
        for (int j = 0; j < 4; ++j) {
            const unsigned int y   = (unsigned int)(j * 64 + lane);
            const unsigned int tag = genHi | y;
            const float vr = rrow[j * 64 + lane];
            const float vt = trow[j * 64 + lane];
            if (vr != 0.0f) {
                int t = (int)(vr * 1000.0f) - 1;   // trunc == astype(int32)
                if (t < 0) t += TIMESTEPS;         // python wrap: -1 -> 999
                if ((unsigned)t < TIMESTEPS) hr[t] = tag;
            }
            if (vt != 0.0f) {
                int t = (int)(vt * 1000.0f) - 1;
                if (t < 0) t += TIMESTEPS;
                if ((unsigned)t < TIMESTEPS) ht[t] = tag;
            }
        }
        __builtin_amdgcn_wave_barrier();   // reads stay after this row's stores

        // scan: contiguous b128 reads; packed-i16 decode + sdot2 accumulate
        const unsigned int genPk = genHi | (genHi << 16);
        #pragma unroll
        for (int k = 0; k < 4; ++k) {
            const uint4 A = *(const uint4*)&hr[k * 256 + lane * 4];
            const uint4 B = *(const uint4*)&ht[k * 256 + lane * 4];
            const unsigned int Aw[4] = {A.x, A.y, A.z, A.w};
            const unsigned int Bw[4] = {B.x, B.y, B.z, B.w};
            #pragma unroll
            for (int h = 0; h < 2; ++h) {
                unsigned int pa = __builtin_amdgcn_perm(Aw[2*h+1], Aw[2*h], 0x05040100u);
                unsigned int pb = __builtin_amdgcn_perm(Bw[2*h+1], Bw[2*h], 0x05040100u);
                s16x2 ya = (s16x2)(pa) - (s16x2)(genPk);
                s16x2 yb = (s16x2)(pb) - (s16x2)(genPk);
                ya = __builtin_elementwise_max(ya, (s16x2)0);  // stale/empty -> 0
                yb = __builtin_elementwise_max(yb, (s16x2)0);
                const s16x2 d = ya - yb;
#if __has_builtin(__builtin_amdgcn_sdot2)
                acc = (unsigned int)__builtin_amdgcn_sdot2(d, d, (int)acc, false);
#else
                acc += (unsigned int)((int)d.x * (int)d.x + (int)d.y * (int)d.y);
#endif
            }
        }
        __builtin_amdgcn_wave_barrier();   // next row's stores stay below reads
    }

    // wave reduce, then one partial per BLOCK (block sum <= 1.05e9, fits u32)
    #pragma unroll
    for (int off = 32; off > 0; off >>= 1) acc += __shfl_down(acc, off, 64);

    __shared__ unsigned int wsum[WAVES_PER_BLOCK];
    if (lane == 0) wsum[wave] = acc;
    __syncthreads();
    if (tid == 0)
        partials[blockIdx.x] = wsum[0] + wsum[1] + wsum[2] + wsum[3];
}

// Single block sums 1024 u32 partials exactly in u64 (4 KB read).
__global__ __launch_bounds__(256) void reduce_kernel(
    const unsigned int* __restrict__ partials, float* __restrict__ out)
{
    const int tid = threadIdx.x;
    const uint4 p = ((const uint4*)partials)[tid];          // 256 * 16B = 4 KB
    unsigned long long s = (unsigned long long)p.x + p.y + p.z + p.w;

    #pragma unroll
    for (int off = 32; off > 0; off >>= 1) s += __shfl_down(s, off, 64);

    __shared__ unsigned long long wsum[4];
    const int wave = tid >> 6;
    if ((tid & 63) == 0) wsum[wave] = s;
    __syncthreads();

    if (tid == 0) {
        unsigned long long tot = wsum[0] + wsum[1] + wsum[2] + wsum[3];
        const double denom = (double)BATCH * (double)HH * (double)TIMESTEPS; // 16,384,000
        out[0] = (float)((double)tot / denom);
    }
}

extern "C" void kernel_launch(void* const* d_in, const int* in_sizes, int n_in,
                              void* d_out, int out_size, void* d_ws, size_t ws_size,
                              hipStream_t stream) {
    const float* rec = (const float*)d_in[0];
    const float* tgt = (const float*)d_in[1];
    float* out = (float*)d_out;
    unsigned int* partials = (unsigned int*)d_ws;   // 1024 * 4 B = 4 KB scratch

    holo_mse_kernel<<<NBLOCKS, 256, 0, stream>>>(rec, tgt, partials);
    reduce_kernel<<<1, 256, 0, stream>>>(partials, out);
}